// Round 2
// baseline (1137.610 us; speedup 1.0000x reference)
//
#include <hip/hip_runtime.h>

// Problem: B=4, Tq=2048, Tk=4096, E=1024, D=128, M=16384, top_k=32
// All inputs/outputs are float32 (reference is pure jnp.float32).

using bf16x8 = __attribute__((ext_vector_type(8))) short;
using f32x4  = __attribute__((ext_vector_type(4))) float;

__device__ __forceinline__ float bf2f(ushort h) {
  union { uint u; float f; } x; x.u = ((uint)h) << 16; return x.f;
}
__device__ __forceinline__ ushort f2bf(float f) {
  union { float f; uint u; } x; x.f = f;
  uint u = x.u;
  u += 0x7fffu + ((u >> 16) & 1u);   // RNE (finite inputs only)
  return (ushort)(u >> 16);
}
// two bf16 halves (packed in a uint) -> order-preserving uint16 keys
__device__ __forceinline__ uint ord2(uint v) {
  uint lo = v & 0xffffu, hi = v >> 16;
  lo = (lo & 0x8000u) ? (0xffffu ^ lo) : (lo | 0x8000u);
  hi = (hi & 0x8000u) ? (0xffffu ^ hi) : (hi | 0x8000u);
  return lo | (hi << 16);
}

// ---- Wth[z][n][k] = bf16(W_z[k][n]) for z=0..2; Wtlq[n][k] = lo(Wq[k][n]) ----
__global__ __launch_bounds__(256) void k_wt(const float* __restrict__ Wq,
                                            const float* __restrict__ Wk,
                                            const float* __restrict__ Wv,
                                            ushort* __restrict__ Wth,
                                            ushort* __restrict__ Wtlq) {
  int id = blockIdx.x * 256 + threadIdx.x;        // 4*131072 = 524288 exact
  int z = id >> 17, r = id & 131071;
  int n = r >> 10, k = r & 1023;
  const float* W = (z == 1) ? Wk : (z == 2) ? Wv : Wq;
  float w = W[k * 128 + n];
  ushort h = f2bf(w);
  if (z < 3) Wth[id] = h;
  else       Wtlq[r] = f2bf(w - bf2f(h));
}

// ---- fp32 -> bf16 bulk convert (8 elems/thread) ----
__global__ __launch_bounds__(256) void k_cvt8(const float* __restrict__ src,
                                              ushort* __restrict__ dst) {
  int id = blockIdx.x * 256 + threadIdx.x;
  size_t base = (size_t)id * 8;
  float4 a = *(const float4*)(src + base);
  float4 b = *(const float4*)(src + base + 4);
  bf16x8 r;
  r[0] = (short)f2bf(a.x); r[1] = (short)f2bf(a.y);
  r[2] = (short)f2bf(a.z); r[3] = (short)f2bf(a.w);
  r[4] = (short)f2bf(b.x); r[5] = (short)f2bf(b.y);
  r[6] = (short)f2bf(b.z); r[7] = (short)f2bf(b.w);
  *(bf16x8*)(dst + base) = r;
}

// ---- prefix: k_full/v_full[b][t<2048][d] = bf16(ki/vi[b][t][idx*128+d]) ----
__global__ __launch_bounds__(256) void k_prefix(const float* __restrict__ ki,
                                                const float* __restrict__ vi,
                                                const int* __restrict__ idx,
                                                ushort* __restrict__ kfull,
                                                ushort* __restrict__ vfull) {
  int s = idx[0] * 128;
  int id = blockIdx.x * 256 + threadIdx.x;        // 131072 chunks of 8
  int d8 = (id & 15) * 8;
  int bt = id >> 4;                                // b*2048+t
  int b = bt >> 11, t = bt & 2047;
  const float* kp = ki + (size_t)bt * 1024 + s + d8;
  const float* vp = vi + (size_t)bt * 1024 + s + d8;
  bf16x8 rk, rv;
#pragma unroll
  for (int j = 0; j < 8; ++j) { rk[j] = (short)f2bf(kp[j]); rv[j] = (short)f2bf(vp[j]); }
  size_t dst = ((size_t)b * 4096 + t) * 128 + d8;
  *(bf16x8*)(kfull + dst) = rk;
  *(bf16x8*)(vfull + dst) = rv;
}

// ---- QKV projection. z=0: hi/lo split (3 MFMAs) -> fp32 qex (near-exact).
//      z=1,2: hi-only MFMA -> bf16 kfull/vfull rows [2048..4096). ----
__global__ __launch_bounds__(256) void k_qkv(const float* __restrict__ x,
                                             const ushort* __restrict__ Wth,
                                             const ushort* __restrict__ Wtlq,
                                             const float* __restrict__ bq,
                                             const float* __restrict__ bk,
                                             const float* __restrict__ bv,
                                             float* __restrict__ qex,
                                             ushort* __restrict__ kfull,
                                             ushort* __restrict__ vfull) {
  int z = blockIdx.y;
  int m0 = blockIdx.x * 64;
  int t = threadIdx.x, lane = t & 63, wv = t >> 6;
  int l15 = lane & 15, q8 = (lane >> 4) * 8;
  const ushort* Wz = Wth + (size_t)z * 131072;
  const float* xrow = x + (size_t)(m0 + wv * 16 + l15) * 1024 + q8;
  f32x4 zero = {0.f, 0.f, 0.f, 0.f};
  f32x4 acc[8] = {zero, zero, zero, zero, zero, zero, zero, zero};
  for (int k0 = 0; k0 < 1024; k0 += 32) {
    float xf[8];
#pragma unroll
    for (int j = 0; j < 8; ++j) xf[j] = xrow[k0 + j];
    bf16x8 ah;
#pragma unroll
    for (int j = 0; j < 8; ++j) ah[j] = (short)f2bf(xf[j]);
    if (z == 0) {
      bf16x8 al;
#pragma unroll
      for (int j = 0; j < 8; ++j) al[j] = (short)f2bf(xf[j] - bf2f((ushort)ah[j]));
#pragma unroll
      for (int nc = 0; nc < 8; ++nc) {
        size_t wo = (size_t)(nc * 16 + l15) * 1024 + k0 + q8;
        bf16x8 bh = *(const bf16x8*)(Wz + wo);
        bf16x8 bl = *(const bf16x8*)(Wtlq + wo);
        acc[nc] = __builtin_amdgcn_mfma_f32_16x16x32_bf16(ah, bh, acc[nc], 0, 0, 0);
        acc[nc] = __builtin_amdgcn_mfma_f32_16x16x32_bf16(ah, bl, acc[nc], 0, 0, 0);
        acc[nc] = __builtin_amdgcn_mfma_f32_16x16x32_bf16(al, bh, acc[nc], 0, 0, 0);
      }
    } else {
#pragma unroll
      for (int nc = 0; nc < 8; ++nc) {
        bf16x8 bh = *(const bf16x8*)(Wz + (size_t)(nc * 16 + l15) * 1024 + k0 + q8);
        acc[nc] = __builtin_amdgcn_mfma_f32_16x16x32_bf16(ah, bh, acc[nc], 0, 0, 0);
      }
    }
  }
  const float* bias = (z == 0) ? bq : (z == 1) ? bk : bv;
  int mrow = m0 + wv * 16 + (lane >> 4) * 4;
#pragma unroll
  for (int nc = 0; nc < 8; ++nc) {
    int n = nc * 16 + l15;
    float bb = bias[n];
#pragma unroll
    for (int r = 0; r < 4; ++r) {
      int m = mrow + r;
      float val = acc[nc][r] + bb;
      if (z == 0) {
        qex[(size_t)m * 128 + n] = val;
      } else {
        int b2 = m >> 11, tt = m & 2047;
        size_t o = ((size_t)b2 * 4096 + 2048 + tt) * 128 + n;
        if (z == 1) kfull[o] = f2bf(val); else vfull[o] = f2bf(val);
      }
    }
  }
}

// ---- Vt[b][d][t] = v_full[b][t][d]  (tiled transpose, bf16) ----
__global__ __launch_bounds__(256) void k_vt(const ushort* __restrict__ vfull,
                                            ushort* __restrict__ Vt) {
  __shared__ ushort lds[64][136];
  int blk = blockIdx.x;                 // 4*64 = 256
  int b = blk >> 6, t0 = (blk & 63) * 64;
  int t = threadIdx.x;
#pragma unroll
  for (int p = 0; p < 4; ++p) {
    int ch = p * 256 + t;               // 1024 chunks of 8 elems
    int row = ch >> 4, c8 = (ch & 15) * 8;
    uint4 v = *(const uint4*)(vfull + ((size_t)b * 4096 + t0 + row) * 128 + c8);
    *(uint4*)(&lds[row][c8]) = v;
  }
  __syncthreads();
#pragma unroll
  for (int p = 0; p < 8; ++p) {
    int q = p * 256 + t;                // 2048 chunks of 4 elems
    int d = q >> 4, t4 = (q & 15) * 4;
    ushort4 o;
    o.x = lds[t4 + 0][d]; o.y = lds[t4 + 1][d];
    o.z = lds[t4 + 2][d]; o.w = lds[t4 + 3][d];
    *(ushort4*)(Vt + ((size_t)b * 128 + d) * 4096 + t0 + t4) = o;
  }
}

// ---- scores GEMM: S[q][n] = bf16(A_f32[q][:]) . Bm_bf16[n][:]  (A.B^T) ----
__global__ __launch_bounds__(256) void k_scores(const float* __restrict__ A,
                                                const ushort* __restrict__ Bm,
                                                ushort* __restrict__ S,
                                                int N, int nslice, int causalOff,
                                                long sA, long sB, long sS) {
  __shared__ ushort Bt[64 * 136];
  int q0 = blockIdx.x * 64;
  int ns0 = blockIdx.y * nslice;
  int nend = ns0 + nslice; if (nend > N) nend = N;
  int climit = q0 + 64 + causalOff; if (nend > climit) nend = climit;
  if (ns0 >= nend) return;
  int zb = blockIdx.z;
  const float*  Ab = A  + (size_t)zb * sA;
  const ushort* Bb = Bm + (size_t)zb * sB;
  ushort* Sb = S + (size_t)zb * sS;
  int t = threadIdx.x, lane = t & 63, wv = t >> 6;
  int l15 = lane & 15, q8 = (lane >> 4) * 8;
  const float* Arow = Ab + (size_t)(q0 + wv * 16 + l15) * 128 + q8;
  bf16x8 af[4];
#pragma unroll
  for (int kc = 0; kc < 4; ++kc)
#pragma unroll
    for (int j = 0; j < 8; ++j) af[kc][j] = (short)f2bf(Arow[kc * 32 + j]);
  for (int n0 = ns0; n0 < nend; n0 += 64) {
#pragma unroll
    for (int p = 0; p < 4; ++p) {
      int ch = p * 256 + t;
      int row = ch >> 4, c8 = (ch & 15) * 8;
      uint4 v = *(const uint4*)(Bb + (size_t)(n0 + row) * 128 + c8);
      *(uint4*)(&Bt[row * 136 + c8]) = v;
    }
    __syncthreads();
    f32x4 zero = {0.f, 0.f, 0.f, 0.f};
    f32x4 acc[4] = {zero, zero, zero, zero};
#pragma unroll
    for (int h = 0; h < 4; ++h) {
#pragma unroll
      for (int kc = 0; kc < 4; ++kc) {
        bf16x8 bfr = *(const bf16x8*)(&Bt[(h * 16 + l15) * 136 + kc * 32 + q8]);
        acc[h] = __builtin_amdgcn_mfma_f32_16x16x32_bf16(af[kc], bfr, acc[h], 0, 0, 0);
      }
    }
    int qq = q0 + wv * 16 + (lane >> 4) * 4;
#pragma unroll
    for (int h = 0; h < 4; ++h)
#pragma unroll
      for (int r = 0; r < 4; ++r)
        Sb[(size_t)(qq + r) * N + (n0 + h * 16 + l15)] = f2bf(acc[h][r]);
    __syncthreads();
  }
}

// ---- windowed softmax in place: P = softmax(S/sqrt(128)), zeros beyond window ----
__global__ __launch_bounds__(256) void k_softmax(ushort* __restrict__ S) {
  int rid = blockIdx.x;                // 0..8191 (b*2048+i)
  int i = rid & 2047;
  ushort* row = S + (size_t)rid * 4096;
  int w = i + 2049;                    // keys j <= i + 2048
  int t = threadIdx.x;
  const float scale = 0.08838834764831845f;  // 1/sqrt(128)
  float v[16];
  float mx = -1e30f;
#pragma unroll
  for (int c = 0; c < 16; ++c) {
    int e = c * 256 + t;
    float f = -1e30f;
    if (e < w) f = bf2f(row[e]) * scale;
    v[c] = f;
    mx = fmaxf(mx, f);
  }
  __shared__ float red[4];
#pragma unroll
  for (int off = 32; off; off >>= 1) mx = fmaxf(mx, __shfl_xor(mx, off));
  if ((t & 63) == 0) red[t >> 6] = mx;
  __syncthreads();
  mx = fmaxf(fmaxf(red[0], red[1]), fmaxf(red[2], red[3]));
  __syncthreads();
  float ex[16];
  float sum = 0.f;
#pragma unroll
  for (int c = 0; c < 16; ++c) {
    int e = c * 256 + t;
    ex[c] = (e < w) ? __expf(v[c] - mx) : 0.f;
    sum += ex[c];
  }
#pragma unroll
  for (int off = 32; off; off >>= 1) sum += __shfl_xor(sum, off);
  if ((t & 63) == 0) red[t >> 6] = sum;
  __syncthreads();
  sum = red[0] + red[1] + red[2] + red[3];
  float inv = 1.f / sum;
#pragma unroll
  for (int c = 0; c < 16; ++c) {
    int e = c * 256 + t;
    row[e] = f2bf(ex[c] * inv);        // exact zeros beyond window
  }
}

// ---- PV: O_f32 = P_bf16[2048x4096] . V[4096x128] via Vt ----
__global__ __launch_bounds__(128) void k_pv(const ushort* __restrict__ P,
                                            const ushort* __restrict__ Vt,
                                            float* __restrict__ O) {
  int b = blockIdx.y;
  int q0 = blockIdx.x * 32;
  int t = threadIdx.x, lane = t & 63, wv = t >> 6;
  int l15 = lane & 15, q8 = (lane >> 4) * 8;
  const ushort* Pb = P + ((size_t)b * 2048 + q0 + wv * 16 + l15) * 4096;
  const ushort* Vb = Vt + (size_t)b * 128 * 4096;
  int kend = q0 + 32 + 2048; if (kend > 4096) kend = 4096;
  f32x4 zero = {0.f, 0.f, 0.f, 0.f};
  f32x4 acc[8] = {zero, zero, zero, zero, zero, zero, zero, zero};
  for (int k0 = 0; k0 < kend; k0 += 32) {
    bf16x8 af = *(const bf16x8*)(Pb + k0 + q8);
#pragma unroll
    for (int nc = 0; nc < 8; ++nc) {
      bf16x8 bfr = *(const bf16x8*)(Vb + (size_t)(nc * 16 + l15) * 4096 + k0 + q8);
      acc[nc] = __builtin_amdgcn_mfma_f32_16x16x32_bf16(af, bfr, acc[nc], 0, 0, 0);
    }
  }
  size_t ob = ((size_t)b * 2048 + q0 + wv * 16 + (lane >> 4) * 4) * 128;
#pragma unroll
  for (int nc = 0; nc < 8; ++nc)
#pragma unroll
    for (int r = 0; r < 4; ++r)
      O[ob + (size_t)r * 128 + nc * 16 + l15] = acc[nc][r];
}

// ---- exact top-32 kNN attention per query (fp32 refinement) ----
__global__ __launch_bounds__(256) void k_topk(const ushort* __restrict__ Sall,
                                              const float* __restrict__ qf32b,
                                              const float* __restrict__ memk,
                                              const float* __restrict__ memv,
                                              float* __restrict__ mout) {
  __shared__ ushort vals[16384];
  __shared__ uint hist[256];
  __shared__ float qf[128];
  __shared__ uint cidx[320];
  __shared__ float csc[320];
  __shared__ uint selIdx[32];
  __shared__ float selS[32];
  __shared__ int sB, sRank, sT, nC;

  int i = blockIdx.x;
  const ushort* Srow = Sall + (size_t)i * 16384;
  int t = threadIdx.x;
  if (t < 128) qf[t] = qf32b[(size_t)i * 128 + t];
  hist[t] = 0;
  if (t == 0) nC = 0;
  __syncthreads();

  // pass 0: load bf16 scores, ordered-key transform, stash, hi-byte histogram
  for (int c = 0; c < 8; ++c) {
    int base = (c * 256 + t) * 8;
    uint4 rv = *(const uint4*)(Srow + base);
    uint a0 = ord2(rv.x), a1 = ord2(rv.y), a2 = ord2(rv.z), a3 = ord2(rv.w);
    uint4 sv; sv.x = a0; sv.y = a1; sv.z = a2; sv.w = a3;
    *(uint4*)(vals + base) = sv;
    atomicAdd(&hist[(a0 & 0xffffu) >> 8], 1u); atomicAdd(&hist[a0 >> 24], 1u);
    atomicAdd(&hist[(a1 & 0xffffu) >> 8], 1u); atomicAdd(&hist[a1 >> 24], 1u);
    atomicAdd(&hist[(a2 & 0xffffu) >> 8], 1u); atomicAdd(&hist[a2 >> 24], 1u);
    atomicAdd(&hist[(a3 & 0xffffu) >> 8], 1u); atomicAdd(&hist[a3 >> 24], 1u);
  }
  __syncthreads();
  // rank-64 superset: absorbs bf16 score noise (sigma~0.03 vs rank32-64 gap ~2)
  if (t == 0) {
    int cum = 0; sB = 0; sRank = 64;
    for (int bb = 255; bb >= 0; --bb) {
      int c2 = cum + (int)hist[bb];
      if (c2 >= 64) { sB = bb; sRank = 64 - cum; break; }
      cum = c2;
    }
  }
  __syncthreads();
  int Bb = sB;
  hist[t] = 0;
  __syncthreads();
  // pass 1: low-byte histogram within bucket Bb
  for (int c = 0; c < 8; ++c) {
    int base = (c * 256 + t) * 8;
    uint4 rv = *(const uint4*)(vals + base);
    uint hh[8] = {rv.x & 0xffffu, rv.x >> 16, rv.y & 0xffffu, rv.y >> 16,
                  rv.z & 0xffffu, rv.z >> 16, rv.w & 0xffffu, rv.w >> 16};
#pragma unroll
    for (int j = 0; j < 8; ++j)
      if ((hh[j] >> 8) == (uint)Bb) atomicAdd(&hist[hh[j] & 255u], 1u);
  }
  __syncthreads();
  if (t == 0) {
    int cum = 0, rank = sRank; sT = Bb << 8;
    for (int lb = 255; lb >= 0; --lb) {
      int c2 = cum + (int)hist[lb];
      if (c2 >= rank) { sT = (Bb << 8) | lb; break; }
      cum = c2;
    }
  }
  __syncthreads();
  uint T = (uint)sT;
  // pass 2: compact candidate indices with key >= T (count >= 64)
  for (int c = 0; c < 8; ++c) {
    int base = (c * 256 + t) * 8;
    uint4 rv = *(const uint4*)(vals + base);
    uint hh[8] = {rv.x & 0xffffu, rv.x >> 16, rv.y & 0xffffu, rv.y >> 16,
                  rv.z & 0xffffu, rv.z >> 16, rv.w & 0xffffu, rv.w >> 16};
#pragma unroll
    for (int j = 0; j < 8; ++j) {
      if (hh[j] >= T) {
        int p = atomicAdd(&nC, 1);
        if (p < 320) cidx[p] = (uint)(base + j);
      }
    }
  }
  __syncthreads();
  int C = nC; if (C > 320) C = 320;
  int wv = t >> 6, lane = t & 63;
  // pass 3: exact fp32 scores (fp32 q . fp32 mem_keys, matches np to ~1e-5)
  for (int j = wv; j < C; j += 4) {
    const float* krow = memk + (size_t)cidx[j] * 128;
    float2 pp = *(const float2*)(krow + lane * 2);
    float s = qf[lane * 2] * pp.x + qf[lane * 2 + 1] * pp.y;
#pragma unroll
    for (int off = 32; off; off >>= 1) s += __shfl_xor(s, off);
    if (lane == 0) csc[j] = s;
  }
  __syncthreads();
  // pass 4: exact top-32 (score desc, index asc) + softmax(s/32), wave 0 only
  if (wv == 0) {
    unsigned long long kv[5];
#pragma unroll
    for (int kk = 0; kk < 5; ++kk) {
      int j = lane + kk * 64;
      if (j < C) {
        uint sb2 = __float_as_uint(csc[j]);
        uint o = (sb2 & 0x80000000u) ? ~sb2 : (sb2 | 0x80000000u);
        kv[kk] = ((unsigned long long)o << 32) | (uint)(~cidx[j]);
      } else kv[kk] = 0ull;
    }
    for (int iter = 0; iter < 32; ++iter) {
      unsigned long long b0 = kv[0]; int bi = 0;
#pragma unroll
      for (int kk = 1; kk < 5; ++kk) if (kv[kk] > b0) { b0 = kv[kk]; bi = kk; }
      unsigned long long m = b0;
#pragma unroll
      for (int off = 32; off; off >>= 1) {
        unsigned long long o2 = __shfl_xor(m, off);
        if (o2 > m) m = o2;
      }
      unsigned long long msk = __ballot(b0 == m);
      int wl = (int)(__ffsll((long long)msk) - 1);
      if (lane == wl) kv[bi] = 0ull;
      if (lane == 0) {
        uint o = (uint)(m >> 32);
        uint sb2 = (o & 0x80000000u) ? (o ^ 0x80000000u) : ~o;
        selS[iter] = __uint_as_float(sb2);
        selIdx[iter] = ~((uint)m);
      }
    }
    float sc = (lane < 32) ? selS[lane] * 0.03125f : -1e30f;  // 1/sqrt(1024)
    float mx = sc;
#pragma unroll
    for (int off = 32; off; off >>= 1) mx = fmaxf(mx, __shfl_xor(mx, off));
    float ex = (lane < 32) ? __expf(sc - mx) : 0.f;
    float Z = ex;
#pragma unroll
    for (int off = 32; off; off >>= 1) Z += __shfl_xor(Z, off);
    if (lane < 32) selS[lane] = ex / Z;
  }
  __syncthreads();
  if (t < 128) {
    float acc = 0.f;
    for (int j = 0; j < 32; ++j)
      acc += selS[j] * memv[(size_t)selIdx[j] * 128 + t];
    mout[(size_t)i * 128 + t] = acc;
  }
}

// ---- final gate mix (fp32 out) ----
__global__ __launch_bounds__(256) void k_mix(const float* __restrict__ a,
                                             const float* __restrict__ b,
                                             const float* __restrict__ gate,
                                             float* __restrict__ out) {
  int id = blockIdx.x * 256 + threadIdx.x;   // 262144 chunks of 4
  float g = gate[0];
  float4 va = ((const float4*)a)[id];
  float4 vb = ((const float4*)b)[id];
  float4 o;
  o.x = va.x * g + vb.x * (1.f - g);
  o.y = va.y * g + vb.y * (1.f - g);
  o.z = va.z * g + vb.z * (1.f - g);
  o.w = va.w * g + vb.w * (1.f - g);
  ((float4*)out)[id] = o;
}

extern "C" void kernel_launch(void* const* d_in, const int* in_sizes, int n_in,
                              void* d_out, int out_size, void* d_ws, size_t ws_size,
                              hipStream_t stream) {
  const float* x    = (const float*)d_in[0];
  const float* ki   = (const float*)d_in[1];
  const float* vi   = (const float*)d_in[2];
  const float* mk   = (const float*)d_in[3];
  const float* mv   = (const float*)d_in[4];
  const float* Wq   = (const float*)d_in[5];
  const float* bq   = (const float*)d_in[6];
  const float* Wk   = (const float*)d_in[7];
  const float* bk   = (const float*)d_in[8];
  const float* Wv   = (const float*)d_in[9];
  const float* bv   = (const float*)d_in[10];
  const float* gate = (const float*)d_in[11];
  const int*   idx  = (const int*)d_in[12];

  char* ws = (char*)d_ws;
  ushort* Sbuf  = (ushort*)(ws);                 // 64 MiB scores (SDPA, then per-batch mem)
  float*  qex   = (float*) (ws + 67108864);      // 4 MiB fp32 q (near-exact)
  ushort* kfull = (ushort*)(ws + 71303168);      // 4 MiB
  ushort* vfull = (ushort*)(ws + 75497472);      // 4 MiB
  ushort* Vt    = (ushort*)(ws + 79691776);      // 4 MiB
  ushort* mkb   = (ushort*)(ws + 83886080);      // 16 MiB bf16 mem_keys
  ushort* Wth   = (ushort*)(ws + 100663296);     // 768 KiB
  ushort* Wtlq  = (ushort*)(ws + 101449728);     // 256 KiB
  float*  osdpa = (float*) (ws + 101711872);     // 4 MiB
  float*  mout  = (float*) (ws + 105906176);     // 4 MiB (end ~105 MiB)

  k_wt<<<2048, 256, 0, stream>>>(Wq, Wk, Wv, Wth, Wtlq);
  k_cvt8<<<4096, 256, 0, stream>>>(mk, mkb);     // 4*16384*128 / 8 / 256
  k_prefix<<<512, 256, 0, stream>>>(ki, vi, idx, kfull, vfull);
  k_qkv<<<dim3(128, 3), 256, 0, stream>>>(x, Wth, Wtlq, bq, bk, bv, qex, kfull, vfull);
  k_vt<<<256, 256, 0, stream>>>(vfull, Vt);

  // SDPA: scores -> windowed softmax (in place) -> PV
  k_scores<<<dim3(32, 4, 4), 256, 0, stream>>>(qex, kfull, Sbuf,
                                               4096, 1024, 2048,
                                               (long)2048 * 128, (long)4096 * 128,
                                               (long)2048 * 4096);
  k_softmax<<<8192, 256, 0, stream>>>(Sbuf);
  k_pv<<<dim3(64, 4), 128, 0, stream>>>(Sbuf, Vt, osdpa);

  // kNN memory attention, per batch (reuses Sbuf)
  for (int b = 0; b < 4; ++b) {
    k_scores<<<dim3(32, 8, 1), 256, 0, stream>>>(qex + (size_t)b * 2048 * 128,
                                                 mkb + (size_t)b * 16384 * 128,
                                                 Sbuf, 16384, 2048, (1 << 28),
                                                 0, 0, 0);
    k_topk<<<2048, 256, 0, stream>>>(Sbuf, qex + (size_t)b * 2048 * 128,
                                     mk + (size_t)b * 16384 * 128,
                                     mv + (size_t)b * 16384 * 128,
                                     mout + (size_t)b * 2048 * 128);
  }

  k_mix<<<1024, 256, 0, stream>>>(osdpa, mout, gate, (float*)d_out);
}

// Round 3
// 871.742 us; speedup vs baseline: 1.3050x; 1.3050x over previous
//
#include <hip/hip_runtime.h>

// Problem: B=4, Tq=2048, Tk=4096, E=1024, D=128, M=16384, top_k=32
// All inputs/outputs are float32 (reference is pure jnp.float32).

using bf16x8 = __attribute__((ext_vector_type(8))) short;
using f32x4  = __attribute__((ext_vector_type(4))) float;

__device__ __forceinline__ float bf2f(ushort h) {
  union { uint u; float f; } x; x.u = ((uint)h) << 16; return x.f;
}
__device__ __forceinline__ ushort f2bf(float f) {
  union { float f; uint u; } x; x.f = f;
  uint u = x.u;
  u += 0x7fffu + ((u >> 16) & 1u);   // RNE (finite inputs only)
  return (ushort)(u >> 16);
}
// two bf16 halves (packed in a uint) -> order-preserving uint16 keys
__device__ __forceinline__ uint ord2(uint v) {
  uint lo = v & 0xffffu, hi = v >> 16;
  lo = (lo & 0x8000u) ? (0xffffu ^ lo) : (lo | 0x8000u);
  hi = (hi & 0x8000u) ? (0xffffu ^ hi) : (hi | 0x8000u);
  return lo | (hi << 16);
}
// bank-remapped address for 2048-bucket LDS histogram
__device__ __forceinline__ int haddr(uint b) {
  return (int)(((b & 7u) << 8) | (b >> 3));
}

// ---- Wth[z][n][k] = bf16(W_z[k][n]) for z=0..2; Wtlq[n][k] = lo(Wq[k][n]) ----
__global__ __launch_bounds__(256) void k_wt(const float* __restrict__ Wq,
                                            const float* __restrict__ Wk,
                                            const float* __restrict__ Wv,
                                            ushort* __restrict__ Wth,
                                            ushort* __restrict__ Wtlq) {
  int id = blockIdx.x * 256 + threadIdx.x;        // 4*131072 = 524288 exact
  int z = id >> 17, r = id & 131071;
  int n = r >> 10, k = r & 1023;
  const float* W = (z == 1) ? Wk : (z == 2) ? Wv : Wq;
  float w = W[k * 128 + n];
  ushort h = f2bf(w);
  if (z < 3) Wth[id] = h;
  else       Wtlq[r] = f2bf(w - bf2f(h));
}

// ---- fp32 -> bf16 bulk convert (8 elems/thread) ----
__global__ __launch_bounds__(256) void k_cvt8(const float* __restrict__ src,
                                              ushort* __restrict__ dst) {
  int id = blockIdx.x * 256 + threadIdx.x;
  size_t base = (size_t)id * 8;
  float4 a = *(const float4*)(src + base);
  float4 b = *(const float4*)(src + base + 4);
  bf16x8 r;
  r[0] = (short)f2bf(a.x); r[1] = (short)f2bf(a.y);
  r[2] = (short)f2bf(a.z); r[3] = (short)f2bf(a.w);
  r[4] = (short)f2bf(b.x); r[5] = (short)f2bf(b.y);
  r[6] = (short)f2bf(b.z); r[7] = (short)f2bf(b.w);
  *(bf16x8*)(dst + base) = r;
}

// ---- prefix: k_full/v_full[b][t<2048][d] = bf16(ki/vi[b][t][idx*128+d]) ----
__global__ __launch_bounds__(256) void k_prefix(const float* __restrict__ ki,
                                                const float* __restrict__ vi,
                                                const int* __restrict__ idx,
                                                ushort* __restrict__ kfull,
                                                ushort* __restrict__ vfull) {
  int s = idx[0] * 128;
  int id = blockIdx.x * 256 + threadIdx.x;        // 131072 chunks of 8
  int d8 = (id & 15) * 8;
  int bt = id >> 4;                                // b*2048+t
  int b = bt >> 11, t = bt & 2047;
  const float* kp = ki + (size_t)bt * 1024 + s + d8;
  const float* vp = vi + (size_t)bt * 1024 + s + d8;
  bf16x8 rk, rv;
#pragma unroll
  for (int j = 0; j < 8; ++j) { rk[j] = (short)f2bf(kp[j]); rv[j] = (short)f2bf(vp[j]); }
  size_t dst = ((size_t)b * 4096 + t) * 128 + d8;
  *(bf16x8*)(kfull + dst) = rk;
  *(bf16x8*)(vfull + dst) = rv;
}

// ---- QKV projection. z=0: hi/lo split (3 MFMAs) -> fp32 qex (near-exact).
//      z=1,2: hi-only MFMA -> bf16 kfull/vfull rows [2048..4096). ----
__global__ __launch_bounds__(256) void k_qkv(const float* __restrict__ x,
                                             const ushort* __restrict__ Wth,
                                             const ushort* __restrict__ Wtlq,
                                             const float* __restrict__ bq,
                                             const float* __restrict__ bk,
                                             const float* __restrict__ bv,
                                             float* __restrict__ qex,
                                             ushort* __restrict__ kfull,
                                             ushort* __restrict__ vfull) {
  int z = blockIdx.y;
  int m0 = blockIdx.x * 64;
  int t = threadIdx.x, lane = t & 63, wv = t >> 6;
  int l15 = lane & 15, q8 = (lane >> 4) * 8;
  const ushort* Wz = Wth + (size_t)z * 131072;
  const float* xrow = x + (size_t)(m0 + wv * 16 + l15) * 1024 + q8;
  f32x4 zero = {0.f, 0.f, 0.f, 0.f};
  f32x4 acc[8] = {zero, zero, zero, zero, zero, zero, zero, zero};
  for (int k0 = 0; k0 < 1024; k0 += 32) {
    float xf[8];
#pragma unroll
    for (int j = 0; j < 8; ++j) xf[j] = xrow[k0 + j];
    bf16x8 ah;
#pragma unroll
    for (int j = 0; j < 8; ++j) ah[j] = (short)f2bf(xf[j]);
    if (z == 0) {
      bf16x8 al;
#pragma unroll
      for (int j = 0; j < 8; ++j) al[j] = (short)f2bf(xf[j] - bf2f((ushort)ah[j]));
#pragma unroll
      for (int nc = 0; nc < 8; ++nc) {
        size_t wo = (size_t)(nc * 16 + l15) * 1024 + k0 + q8;
        bf16x8 bh = *(const bf16x8*)(Wz + wo);
        bf16x8 bl = *(const bf16x8*)(Wtlq + wo);
        acc[nc] = __builtin_amdgcn_mfma_f32_16x16x32_bf16(ah, bh, acc[nc], 0, 0, 0);
        acc[nc] = __builtin_amdgcn_mfma_f32_16x16x32_bf16(ah, bl, acc[nc], 0, 0, 0);
        acc[nc] = __builtin_amdgcn_mfma_f32_16x16x32_bf16(al, bh, acc[nc], 0, 0, 0);
      }
    } else {
#pragma unroll
      for (int nc = 0; nc < 8; ++nc) {
        bf16x8 bh = *(const bf16x8*)(Wz + (size_t)(nc * 16 + l15) * 1024 + k0 + q8);
        acc[nc] = __builtin_amdgcn_mfma_f32_16x16x32_bf16(ah, bh, acc[nc], 0, 0, 0);
      }
    }
  }
  const float* bias = (z == 0) ? bq : (z == 1) ? bk : bv;
  int mrow = m0 + wv * 16 + (lane >> 4) * 4;
#pragma unroll
  for (int nc = 0; nc < 8; ++nc) {
    int n = nc * 16 + l15;
    float bb = bias[n];
#pragma unroll
    for (int r = 0; r < 4; ++r) {
      int m = mrow + r;
      float val = acc[nc][r] + bb;
      if (z == 0) {
        qex[(size_t)m * 128 + n] = val;
      } else {
        int b2 = m >> 11, tt = m & 2047;
        size_t o = ((size_t)b2 * 4096 + 2048 + tt) * 128 + n;
        if (z == 1) kfull[o] = f2bf(val); else vfull[o] = f2bf(val);
      }
    }
  }
}

// ---- Vt[b][d][t] = v_full[b][t][d]  (tiled transpose, bf16) ----
__global__ __launch_bounds__(256) void k_vt(const ushort* __restrict__ vfull,
                                            ushort* __restrict__ Vt) {
  __shared__ ushort lds[64][136];
  int blk = blockIdx.x;                 // 4*64 = 256
  int b = blk >> 6, t0 = (blk & 63) * 64;
  int t = threadIdx.x;
#pragma unroll
  for (int p = 0; p < 4; ++p) {
    int ch = p * 256 + t;               // 1024 chunks of 8 elems
    int row = ch >> 4, c8 = (ch & 15) * 8;
    uint4 v = *(const uint4*)(vfull + ((size_t)b * 4096 + t0 + row) * 128 + c8);
    *(uint4*)(&lds[row][c8]) = v;
  }
  __syncthreads();
#pragma unroll
  for (int p = 0; p < 8; ++p) {
    int q = p * 256 + t;                // 2048 chunks of 4 elems
    int d = q >> 4, t4 = (q & 15) * 4;
    ushort4 o;
    o.x = lds[t4 + 0][d]; o.y = lds[t4 + 1][d];
    o.z = lds[t4 + 2][d]; o.w = lds[t4 + 3][d];
    *(ushort4*)(Vt + ((size_t)b * 128 + d) * 4096 + t0 + t4) = o;
  }
}

// ---- scores GEMM: S[q][n] = bf16(A_f32[q][:]) . Bm_bf16[n][:]  (A.B^T) ----
__global__ __launch_bounds__(256) void k_scores(const float* __restrict__ A,
                                                const ushort* __restrict__ Bm,
                                                ushort* __restrict__ S,
                                                int N, int nslice, int causalOff,
                                                long sA, long sB, long sS) {
  __shared__ ushort Bt[64 * 136];
  int q0 = blockIdx.x * 64;
  int ns0 = blockIdx.y * nslice;
  int nend = ns0 + nslice; if (nend > N) nend = N;
  int climit = q0 + 64 + causalOff; if (nend > climit) nend = climit;
  if (ns0 >= nend) return;
  int zb = blockIdx.z;
  const float*  Ab = A  + (size_t)zb * sA;
  const ushort* Bb = Bm + (size_t)zb * sB;
  ushort* Sb = S + (size_t)zb * sS;
  int t = threadIdx.x, lane = t & 63, wv = t >> 6;
  int l15 = lane & 15, q8 = (lane >> 4) * 8;
  const float* Arow = Ab + (size_t)(q0 + wv * 16 + l15) * 128 + q8;
  bf16x8 af[4];
#pragma unroll
  for (int kc = 0; kc < 4; ++kc)
#pragma unroll
    for (int j = 0; j < 8; ++j) af[kc][j] = (short)f2bf(Arow[kc * 32 + j]);
  for (int n0 = ns0; n0 < nend; n0 += 64) {
#pragma unroll
    for (int p = 0; p < 4; ++p) {
      int ch = p * 256 + t;
      int row = ch >> 4, c8 = (ch & 15) * 8;
      uint4 v = *(const uint4*)(Bb + (size_t)(n0 + row) * 128 + c8);
      *(uint4*)(&Bt[row * 136 + c8]) = v;
    }
    __syncthreads();
    f32x4 zero = {0.f, 0.f, 0.f, 0.f};
    f32x4 acc[4] = {zero, zero, zero, zero};
#pragma unroll
    for (int h = 0; h < 4; ++h) {
#pragma unroll
      for (int kc = 0; kc < 4; ++kc) {
        bf16x8 bfr = *(const bf16x8*)(&Bt[(h * 16 + l15) * 136 + kc * 32 + q8]);
        acc[h] = __builtin_amdgcn_mfma_f32_16x16x32_bf16(af[kc], bfr, acc[h], 0, 0, 0);
      }
    }
    int qq = q0 + wv * 16 + (lane >> 4) * 4;
#pragma unroll
    for (int h = 0; h < 4; ++h)
#pragma unroll
      for (int r = 0; r < 4; ++r)
        Sb[(size_t)(qq + r) * N + (n0 + h * 16 + l15)] = f2bf(acc[h][r]);
    __syncthreads();
  }
}

// ---- windowed softmax in place: P = softmax(S/sqrt(128)), zeros beyond window ----
__global__ __launch_bounds__(256) void k_softmax(ushort* __restrict__ S) {
  int rid = blockIdx.x;                // 0..8191 (b*2048+i)
  int i = rid & 2047;
  ushort* row = S + (size_t)rid * 4096;
  int w = i + 2049;                    // keys j <= i + 2048
  int t = threadIdx.x;
  const float scale = 0.08838834764831845f;  // 1/sqrt(128)
  float v[16];
  float mx = -1e30f;
#pragma unroll
  for (int c = 0; c < 16; ++c) {
    int e = c * 256 + t;
    float f = -1e30f;
    if (e < w) f = bf2f(row[e]) * scale;
    v[c] = f;
    mx = fmaxf(mx, f);
  }
  __shared__ float red[4];
#pragma unroll
  for (int off = 32; off; off >>= 1) mx = fmaxf(mx, __shfl_xor(mx, off));
  if ((t & 63) == 0) red[t >> 6] = mx;
  __syncthreads();
  mx = fmaxf(fmaxf(red[0], red[1]), fmaxf(red[2], red[3]));
  __syncthreads();
  float ex[16];
  float sum = 0.f;
#pragma unroll
  for (int c = 0; c < 16; ++c) {
    int e = c * 256 + t;
    ex[c] = (e < w) ? __expf(v[c] - mx) : 0.f;
    sum += ex[c];
  }
#pragma unroll
  for (int off = 32; off; off >>= 1) sum += __shfl_xor(sum, off);
  if ((t & 63) == 0) red[t >> 6] = sum;
  __syncthreads();
  sum = red[0] + red[1] + red[2] + red[3];
  float inv = 1.f / sum;
#pragma unroll
  for (int c = 0; c < 16; ++c) {
    int e = c * 256 + t;
    row[e] = f2bf(ex[c] * inv);        // exact zeros beyond window
  }
}

// ---- PV: O_f32 = P_bf16[2048x4096] . V[4096x128] via Vt; d split over y ----
__global__ __launch_bounds__(128) void k_pv(const ushort* __restrict__ P,
                                            const ushort* __restrict__ Vt,
                                            float* __restrict__ O) {
  int b = blockIdx.z;
  int d0 = blockIdx.y * 64;
  int q0 = blockIdx.x * 32;
  int t = threadIdx.x, lane = t & 63, wv = t >> 6;
  int l15 = lane & 15, q8 = (lane >> 4) * 8;
  const ushort* Pb = P + ((size_t)b * 2048 + q0 + wv * 16 + l15) * 4096;
  const ushort* Vb = Vt + (size_t)b * 128 * 4096;
  int kend = q0 + 32 + 2048; if (kend > 4096) kend = 4096;
  f32x4 zero = {0.f, 0.f, 0.f, 0.f};
  f32x4 acc[4] = {zero, zero, zero, zero};
  for (int k0 = 0; k0 < kend; k0 += 32) {
    bf16x8 af = *(const bf16x8*)(Pb + k0 + q8);
#pragma unroll
    for (int nc = 0; nc < 4; ++nc) {
      bf16x8 bfr = *(const bf16x8*)(Vb + (size_t)(d0 + nc * 16 + l15) * 4096 + k0 + q8);
      acc[nc] = __builtin_amdgcn_mfma_f32_16x16x32_bf16(af, bfr, acc[nc], 0, 0, 0);
    }
  }
  size_t ob = ((size_t)b * 2048 + q0 + wv * 16 + (lane >> 4) * 4) * 128;
#pragma unroll
  for (int nc = 0; nc < 4; ++nc)
#pragma unroll
    for (int r = 0; r < 4; ++r)
      O[ob + (size_t)r * 128 + d0 + nc * 16 + l15] = acc[nc][r];
}

// ---- exact top-32 kNN attention per query: 11-bit radix + parallel scan ----
__global__ __launch_bounds__(256) void k_topk(const ushort* __restrict__ Sall,
                                              const float* __restrict__ qf32b,
                                              const float* __restrict__ memk,
                                              const float* __restrict__ memv,
                                              float* __restrict__ mout) {
  __shared__ uint hist[2048];          // bank-remapped
  __shared__ uint sarr[256];
  __shared__ float qf[128];
  __shared__ uint cidx[384];
  __shared__ float csc[384];
  __shared__ unsigned long long ckey[384];
  __shared__ uint selIdx[32];
  __shared__ float selS[32];
  __shared__ float obuf[256];
  __shared__ int sThr, nC;

  int i = blockIdx.x;
  const ushort* Srow = Sall + (size_t)i * 16384;
  int t = threadIdx.x;
  if (t < 128) qf[t] = qf32b[(size_t)i * 128 + t];
#pragma unroll
  for (int j = 0; j < 8; ++j) hist[j * 256 + t] = 0;
  if (t == 0) nC = 0;
  __syncthreads();

  // pass A: stream scores, 11-bit bucket histogram (bucket = ordkey >> 5)
  for (int c = 0; c < 8; ++c) {
    int base = (c * 256 + t) * 8;
    uint4 rv = *(const uint4*)(Srow + base);
    uint a0 = ord2(rv.x), a1 = ord2(rv.y), a2 = ord2(rv.z), a3 = ord2(rv.w);
    atomicAdd(&hist[haddr((a0 & 0xffffu) >> 5)], 1u); atomicAdd(&hist[haddr(a0 >> 21)], 1u);
    atomicAdd(&hist[haddr((a1 & 0xffffu) >> 5)], 1u); atomicAdd(&hist[haddr(a1 >> 21)], 1u);
    atomicAdd(&hist[haddr((a2 & 0xffffu) >> 5)], 1u); atomicAdd(&hist[haddr(a2 >> 21)], 1u);
    atomicAdd(&hist[haddr((a3 & 0xffffu) >> 5)], 1u); atomicAdd(&hist[haddr(a3 >> 21)], 1u);
  }
  __syncthreads();
  // per-thread suffix over its 8 buckets (bucket b = t*8+j lives at hist[j*256+t])
  uint loc[8];
  {
    uint s = 0;
#pragma unroll
    for (int j = 7; j >= 0; --j) { s += hist[j * 256 + t]; loc[j] = s; }
    sarr[t] = s;
    __syncthreads();
    // Hillis-Steele inclusive suffix across 256 threads
    for (int off = 1; off < 256; off <<= 1) {
      uint v = sarr[t] + ((t + off < 256) ? sarr[t + off] : 0u);
      __syncthreads();
      sarr[t] = v;
      __syncthreads();
    }
    uint above = sarr[t] - s;          // sum over threads > t
    // find max bucket b with C(b) >= 64  (C decreasing in b)
#pragma unroll
    for (int j = 0; j < 8; ++j) {
      uint Cb = loc[j] + above;
      uint Cn = ((j < 7) ? loc[j + 1] : 0u) + above;
      if (Cb >= 64u && Cn < 64u) sThr = ((t * 8 + j) << 5);
    }
  }
  __syncthreads();
  uint T = (uint)sThr;
  // pass B: compact candidate indices with ordkey >= T (count in [64, ~80])
  for (int c = 0; c < 8; ++c) {
    int base = (c * 256 + t) * 8;
    uint4 rv = *(const uint4*)(Srow + base);
    uint hh[8] = {ord2(rv.x) & 0xffffu, ord2(rv.x) >> 16,
                  ord2(rv.y) & 0xffffu, ord2(rv.y) >> 16,
                  ord2(rv.z) & 0xffffu, ord2(rv.z) >> 16,
                  ord2(rv.w) & 0xffffu, ord2(rv.w) >> 16};
#pragma unroll
    for (int j = 0; j < 8; ++j) {
      if (hh[j] >= T) {
        int p = atomicAdd(&nC, 1);
        if (p < 384) cidx[p] = (uint)(base + j);
      }
    }
  }
  __syncthreads();
  int C = nC; if (C > 384) C = 384;
  int wv = t >> 6, lane = t & 63;
  // refine: exact fp32 scores (identical reduction order to validated round-2)
  for (int j = wv; j < C; j += 4) {
    const float* krow = memk + (size_t)cidx[j] * 128;
    float2 pp = *(const float2*)(krow + lane * 2);
    float s = qf[lane * 2] * pp.x + qf[lane * 2 + 1] * pp.y;
#pragma unroll
    for (int off = 32; off; off >>= 1) s += __shfl_xor(s, off);
    if (lane == 0) csc[j] = s;
  }
  __syncthreads();
  // rank-by-counting top-32 (comparator: score desc, index asc — same as round-2)
  for (int j = t; j < C; j += 256) {
    uint sb2 = __float_as_uint(csc[j]);
    uint o = (sb2 & 0x80000000u) ? ~sb2 : (sb2 | 0x80000000u);
    ckey[j] = ((unsigned long long)o << 32) | (uint)(~cidx[j]);
  }
  __syncthreads();
  for (int j = t; j < C; j += 256) {
    unsigned long long my = ckey[j];
    int rank = 0;
    for (int l = 0; l < C; ++l) rank += (ckey[l] > my) ? 1 : 0;
    if (rank < 32) { selS[rank] = csc[j]; selIdx[rank] = cidx[j]; }
  }
  __syncthreads();
  // softmax over the 32 (wave 0, identical math to round-2)
  if (wv == 0) {
    float sc = (lane < 32) ? selS[lane] * 0.03125f : -1e30f;  // 1/sqrt(1024)
    float mx = sc;
#pragma unroll
    for (int off = 32; off; off >>= 1) mx = fmaxf(mx, __shfl_xor(mx, off));
    float ex = (lane < 32) ? __expf(sc - mx) : 0.f;
    float Z = ex;
#pragma unroll
    for (int off = 32; off; off >>= 1) Z += __shfl_xor(Z, off);
    if (lane < 32) selS[lane] = ex / Z;
  }
  __syncthreads();
  // gather: 256 threads, two j-halves per output element
  {
    int d = t & 127, half = t >> 7;
    float acc = 0.f;
    for (int j = half * 16; j < half * 16 + 16; ++j)
      acc += selS[j] * memv[(size_t)selIdx[j] * 128 + d];
    obuf[t] = acc;
  }
  __syncthreads();
  if (t < 128) mout[(size_t)i * 128 + t] = obuf[t] + obuf[t + 128];
}

// ---- final gate mix (fp32 out) ----
__global__ __launch_bounds__(256) void k_mix(const float* __restrict__ a,
                                             const float* __restrict__ b,
                                             const float* __restrict__ gate,
                                             float* __restrict__ out) {
  int id = blockIdx.x * 256 + threadIdx.x;   // 262144 chunks of 4
  float g = gate[0];
  float4 va = ((const float4*)a)[id];
  float4 vb = ((const float4*)b)[id];
  float4 o;
  o.x = va.x * g + vb.x * (1.f - g);
  o.y = va.y * g + vb.y * (1.f - g);
  o.z = va.z * g + vb.z * (1.f - g);
  o.w = va.w * g + vb.w * (1.f - g);
  ((float4*)out)[id] = o;
}

extern "C" void kernel_launch(void* const* d_in, const int* in_sizes, int n_in,
                              void* d_out, int out_size, void* d_ws, size_t ws_size,
                              hipStream_t stream) {
  const float* x    = (const float*)d_in[0];
  const float* ki   = (const float*)d_in[1];
  const float* vi   = (const float*)d_in[2];
  const float* mk   = (const float*)d_in[3];
  const float* mv   = (const float*)d_in[4];
  const float* Wq   = (const float*)d_in[5];
  const float* bq   = (const float*)d_in[6];
  const float* Wk   = (const float*)d_in[7];
  const float* bk   = (const float*)d_in[8];
  const float* Wv   = (const float*)d_in[9];
  const float* bv   = (const float*)d_in[10];
  const float* gate = (const float*)d_in[11];
  const int*   idx  = (const int*)d_in[12];

  char* ws = (char*)d_ws;
  ushort* Sbuf  = (ushort*)(ws);                 // 64 MiB scores (SDPA, then per-batch mem)
  float*  qex   = (float*) (ws + 67108864);      // 4 MiB fp32 q (near-exact)
  ushort* kfull = (ushort*)(ws + 71303168);      // 4 MiB
  ushort* vfull = (ushort*)(ws + 75497472);      // 4 MiB
  ushort* Vt    = (ushort*)(ws + 79691776);      // 4 MiB
  ushort* mkb   = (ushort*)(ws + 83886080);      // 16 MiB bf16 mem_keys
  ushort* Wth   = (ushort*)(ws + 100663296);     // 768 KiB
  ushort* Wtlq  = (ushort*)(ws + 101449728);     // 256 KiB
  float*  osdpa = (float*) (ws + 101711872);     // 4 MiB
  float*  mout  = (float*) (ws + 105906176);     // 4 MiB (end ~105 MiB)

  k_wt<<<2048, 256, 0, stream>>>(Wq, Wk, Wv, Wth, Wtlq);
  k_cvt8<<<4096, 256, 0, stream>>>(mk, mkb);     // 4*16384*128 / 8 / 256
  k_prefix<<<512, 256, 0, stream>>>(ki, vi, idx, kfull, vfull);
  k_qkv<<<dim3(128, 3), 256, 0, stream>>>(x, Wth, Wtlq, bq, bk, bv, qex, kfull, vfull);
  k_vt<<<256, 256, 0, stream>>>(vfull, Vt);

  // SDPA: scores -> windowed softmax (in place) -> PV
  k_scores<<<dim3(32, 4, 4), 256, 0, stream>>>(qex, kfull, Sbuf,
                                               4096, 1024, 2048,
                                               (long)2048 * 128, (long)4096 * 128,
                                               (long)2048 * 4096);
  k_softmax<<<8192, 256, 0, stream>>>(Sbuf);
  k_pv<<<dim3(64, 2, 4), 128, 0, stream>>>(Sbuf, Vt, osdpa);

  // kNN memory attention, per batch (reuses Sbuf)
  for (int b = 0; b < 4; ++b) {
    k_scores<<<dim3(32, 8, 1), 256, 0, stream>>>(qex + (size_t)b * 2048 * 128,
                                                 mkb + (size_t)b * 16384 * 128,
                                                 Sbuf, 16384, 2048, (1 << 28),
                                                 0, 0, 0);
    k_topk<<<2048, 256, 0, stream>>>(Sbuf, qex + (size_t)b * 2048 * 128,
                                     mk + (size_t)b * 16384 * 128,
                                     mv + (size_t)b * 16384 * 128,
                                     mout + (size_t)b * 2048 * 128);
  }

  k_mix<<<1024, 256, 0, stream>>>(osdpa, mout, gate, (float*)d_out);
}

// Round 5
// 838.612 us; speedup vs baseline: 1.3565x; 1.0395x over previous
//
#include <hip/hip_runtime.h>

// Problem: B=4, Tq=2048, Tk=4096, E=1024, D=128, M=16384, top_k=32
// All inputs/outputs are float32 (reference is pure jnp.float32).
// NOTE: qex bits are load-bearing for the top-k boundary (round-4 post-mortem).
// The q-path (k_wt, k_xsplit, k_qkv3 z=0) must stay bit-identical to round 3.

using bf16x8 = __attribute__((ext_vector_type(8))) short;
using f32x4  = __attribute__((ext_vector_type(4))) float;

__device__ __forceinline__ float bf2f(ushort h) {
  union { uint u; float f; } x; x.u = ((uint)h) << 16; return x.f;
}
__device__ __forceinline__ ushort f2bf(float f) {
  union { float f; uint u; } x; x.f = f;
  uint u = x.u;
  u += 0x7fffu + ((u >> 16) & 1u);   // RNE (finite inputs only)
  return (ushort)(u >> 16);
}
// two bf16 halves (packed in a uint) -> order-preserving uint16 keys
__device__ __forceinline__ uint ord2(uint v) {
  uint lo = v & 0xffffu, hi = v >> 16;
  lo = (lo & 0x8000u) ? (0xffffu ^ lo) : (lo | 0x8000u);
  hi = (hi & 0x8000u) ? (0xffffu ^ hi) : (hi | 0x8000u);
  return lo | (hi << 16);
}
// bank-remapped address for 2048-bucket LDS histogram
__device__ __forceinline__ int haddr(uint b) {
  return (int)(((b & 7u) << 8) | (b >> 3));
}

// ---- Wth[z][n][k] = bf16(W_z[k][n]) for z=0..2; Wtlq[n][k] = lo(Wq[k][n]) ----
__global__ __launch_bounds__(256) void k_wt(const float* __restrict__ Wq,
                                            const float* __restrict__ Wk,
                                            const float* __restrict__ Wv,
                                            ushort* __restrict__ Wth,
                                            ushort* __restrict__ Wtlq) {
  int id = blockIdx.x * 256 + threadIdx.x;        // 4*131072 = 524288 exact
  int z = id >> 17, r = id & 131071;
  int n = r >> 10, k = r & 1023;
  const float* W = (z == 1) ? Wk : (z == 2) ? Wv : Wq;
  float w = W[k * 128 + n];
  ushort h = f2bf(w);
  if (z < 3) Wth[id] = h;
  else       Wtlq[r] = f2bf(w - bf2f(h));
}

// ---- fp32 -> bf16 bulk convert (8 elems/thread) ----
__global__ __launch_bounds__(256) void k_cvt8(const float* __restrict__ src,
                                              ushort* __restrict__ dst) {
  int id = blockIdx.x * 256 + threadIdx.x;
  size_t base = (size_t)id * 8;
  float4 a = *(const float4*)(src + base);
  float4 b = *(const float4*)(src + base + 4);
  bf16x8 r;
  r[0] = (short)f2bf(a.x); r[1] = (short)f2bf(a.y);
  r[2] = (short)f2bf(a.z); r[3] = (short)f2bf(a.w);
  r[4] = (short)f2bf(b.x); r[5] = (short)f2bf(b.y);
  r[6] = (short)f2bf(b.z); r[7] = (short)f2bf(b.w);
  *(bf16x8*)(dst + base) = r;
}

// ---- x -> xh (hi bf16), xl (lo bf16); formulas bit-identical to round-3 in-kernel ----
__global__ __launch_bounds__(256) void k_xsplit(const float* __restrict__ x,
                                                ushort* __restrict__ xh,
                                                ushort* __restrict__ xl) {
  int id = blockIdx.x * 256 + threadIdx.x;       // 4096*256 threads, 8 elems each
  size_t base = (size_t)id * 8;
  float4 a = *(const float4*)(x + base);
  float4 b = *(const float4*)(x + base + 4);
  float xf[8] = {a.x, a.y, a.z, a.w, b.x, b.y, b.z, b.w};
  bf16x8 rh, rl;
#pragma unroll
  for (int j = 0; j < 8; ++j) {
    ushort h = f2bf(xf[j]);
    rh[j] = (short)h;
    rl[j] = (short)f2bf(xf[j] - bf2f(h));
  }
  *(bf16x8*)(xh + base) = rh;
  *(bf16x8*)(xl + base) = rl;
}

// ---- prefix: k_full/v_full[b][t<2048][d] = bf16(ki/vi[b][t][idx*128+d]) ----
__global__ __launch_bounds__(256) void k_prefix(const float* __restrict__ ki,
                                                const float* __restrict__ vi,
                                                const int* __restrict__ idx,
                                                ushort* __restrict__ kfull,
                                                ushort* __restrict__ vfull) {
  int s = idx[0] * 128;
  int id = blockIdx.x * 256 + threadIdx.x;        // 131072 chunks of 8
  int d8 = (id & 15) * 8;
  int bt = id >> 4;                                // b*2048+t
  int b = bt >> 11, t = bt & 2047;
  const float* kp = ki + (size_t)bt * 1024 + s + d8;
  const float* vp = vi + (size_t)bt * 1024 + s + d8;
  bf16x8 rk, rv;
#pragma unroll
  for (int j = 0; j < 8; ++j) { rk[j] = (short)f2bf(kp[j]); rv[j] = (short)f2bf(vp[j]); }
  size_t dst = ((size_t)b * 4096 + t) * 128 + d8;
  *(bf16x8*)(kfull + dst) = rk;
  *(bf16x8*)(vfull + dst) = rv;
}

// ---- QKV projection, one wave per 16 rows. Bit-identical math to round-3 k_qkv:
//      z=0: interleaved ah.bh, ah.bl, al.bh over full K=1024 -> fp32 qex
//      z=1,2: ah.bh -> bf16 kfull/vfull rows [2048..4096) ----
__global__ __launch_bounds__(64) void k_qkv3(const ushort* __restrict__ xh,
                                             const ushort* __restrict__ xl,
                                             const ushort* __restrict__ Wth,
                                             const ushort* __restrict__ Wtlq,
                                             const float* __restrict__ bq,
                                             const float* __restrict__ bk,
                                             const float* __restrict__ bv,
                                             float* __restrict__ qex,
                                             ushort* __restrict__ kfull,
                                             ushort* __restrict__ vfull) {
  int z = blockIdx.y;
  int m0 = blockIdx.x * 16;                      // 512 tiles of 16 rows
  int lane = threadIdx.x;                        // one wave
  int l15 = lane & 15, q8 = (lane >> 4) * 8;
  const ushort* Wz = Wth + (size_t)z * 131072;
  const ushort* xhr = xh + (size_t)(m0 + l15) * 1024 + q8;
  const ushort* xlr = xl + (size_t)(m0 + l15) * 1024 + q8;
  f32x4 zero = {0.f, 0.f, 0.f, 0.f};
  f32x4 acc[8] = {zero, zero, zero, zero, zero, zero, zero, zero};
  if (z == 0) {
    for (int k0 = 0; k0 < 1024; k0 += 32) {
      bf16x8 ah = *(const bf16x8*)(xhr + k0);
      bf16x8 al = *(const bf16x8*)(xlr + k0);
#pragma unroll
      for (int nc = 0; nc < 8; ++nc) {
        size_t wo = (size_t)(nc * 16 + l15) * 1024 + k0 + q8;
        bf16x8 bh = *(const bf16x8*)(Wz + wo);
        bf16x8 bl = *(const bf16x8*)(Wtlq + wo);
        acc[nc] = __builtin_amdgcn_mfma_f32_16x16x32_bf16(ah, bh, acc[nc], 0, 0, 0);
        acc[nc] = __builtin_amdgcn_mfma_f32_16x16x32_bf16(ah, bl, acc[nc], 0, 0, 0);
        acc[nc] = __builtin_amdgcn_mfma_f32_16x16x32_bf16(al, bh, acc[nc], 0, 0, 0);
      }
    }
  } else {
    for (int k0 = 0; k0 < 1024; k0 += 32) {
      bf16x8 ah = *(const bf16x8*)(xhr + k0);
#pragma unroll
      for (int nc = 0; nc < 8; ++nc) {
        bf16x8 bh = *(const bf16x8*)(Wz + (size_t)(nc * 16 + l15) * 1024 + k0 + q8);
        acc[nc] = __builtin_amdgcn_mfma_f32_16x16x32_bf16(ah, bh, acc[nc], 0, 0, 0);
      }
    }
  }
  const float* bias = (z == 0) ? bq : (z == 1) ? bk : bv;
  int mrow = m0 + (lane >> 4) * 4;
#pragma unroll
  for (int nc = 0; nc < 8; ++nc) {
    int n = nc * 16 + l15;
    float bb = bias[n];
#pragma unroll
    for (int r = 0; r < 4; ++r) {
      int m = mrow + r;
      float val = acc[nc][r] + bb;
      if (z == 0) {
        qex[(size_t)m * 128 + n] = val;
      } else {
        int b2 = m >> 11, tt = m & 2047;
        size_t o = ((size_t)b2 * 4096 + 2048 + tt) * 128 + n;
        if (z == 1) kfull[o] = f2bf(val); else vfull[o] = f2bf(val);
      }
    }
  }
}

// ---- Vt[b][d][t] = v_full[b][t][d]  (tiled transpose, bf16) ----
__global__ __launch_bounds__(256) void k_vt(const ushort* __restrict__ vfull,
                                            ushort* __restrict__ Vt) {
  __shared__ ushort lds[64][136];
  int blk = blockIdx.x;                 // 4*64 = 256
  int b = blk >> 6, t0 = (blk & 63) * 64;
  int t = threadIdx.x;
#pragma unroll
  for (int p = 0; p < 4; ++p) {
    int ch = p * 256 + t;               // 1024 chunks of 8 elems
    int row = ch >> 4, c8 = (ch & 15) * 8;
    uint4 v = *(const uint4*)(vfull + ((size_t)b * 4096 + t0 + row) * 128 + c8);
    *(uint4*)(&lds[row][c8]) = v;
  }
  __syncthreads();
#pragma unroll
  for (int p = 0; p < 8; ++p) {
    int q = p * 256 + t;                // 2048 chunks of 4 elems
    int d = q >> 4, t4 = (q & 15) * 4;
    ushort4 o;
    o.x = lds[t4 + 0][d]; o.y = lds[t4 + 1][d];
    o.z = lds[t4 + 2][d]; o.w = lds[t4 + 3][d];
    *(ushort4*)(Vt + ((size_t)b * 128 + d) * 4096 + t0 + t4) = o;
  }
}

// ---- scores GEMM: S[q][n] = bf16(A_f32[q][:]) . Bm_bf16[n][:]  (A.B^T) ----
__global__ __launch_bounds__(256) void k_scores(const float* __restrict__ A,
                                                const ushort* __restrict__ Bm,
                                                ushort* __restrict__ S,
                                                int N, int nslice, int causalOff,
                                                long sA, long sB, long sS) {
  __shared__ ushort Bt[64 * 136];
  int q0 = blockIdx.x * 64;
  int ns0 = blockIdx.y * nslice;
  int nend = ns0 + nslice; if (nend > N) nend = N;
  int climit = q0 + 64 + causalOff; if (nend > climit) nend = climit;
  if (ns0 >= nend) return;
  int zb = blockIdx.z;
  const float*  Ab = A  + (size_t)zb * sA;
  const ushort* Bb = Bm + (size_t)zb * sB;
  ushort* Sb = S + (size_t)zb * sS;
  int t = threadIdx.x, lane = t & 63, wv = t >> 6;
  int l15 = lane & 15, q8 = (lane >> 4) * 8;
  const float* Arow = Ab + (size_t)(q0 + wv * 16 + l15) * 128 + q8;
  bf16x8 af[4];
#pragma unroll
  for (int kc = 0; kc < 4; ++kc)
#pragma unroll
    for (int j = 0; j < 8; ++j) af[kc][j] = (short)f2bf(Arow[kc * 32 + j]);
  for (int n0 = ns0; n0 < nend; n0 += 64) {
#pragma unroll
    for (int p = 0; p < 4; ++p) {
      int ch = p * 256 + t;
      int row = ch >> 4, c8 = (ch & 15) * 8;
      uint4 v = *(const uint4*)(Bb + (size_t)(n0 + row) * 128 + c8);
      *(uint4*)(&Bt[row * 136 + c8]) = v;
    }
    __syncthreads();
    f32x4 zero = {0.f, 0.f, 0.f, 0.f};
    f32x4 acc[4] = {zero, zero, zero, zero};
#pragma unroll
    for (int h = 0; h < 4; ++h) {
#pragma unroll
      for (int kc = 0; kc < 4; ++kc) {
        bf16x8 bfr = *(const bf16x8*)(&Bt[(h * 16 + l15) * 136 + kc * 32 + q8]);
        acc[h] = __builtin_amdgcn_mfma_f32_16x16x32_bf16(af[kc], bfr, acc[h], 0, 0, 0);
      }
    }
    int qq = q0 + wv * 16 + (lane >> 4) * 4;
#pragma unroll
    for (int h = 0; h < 4; ++h)
#pragma unroll
      for (int r = 0; r < 4; ++r)
        Sb[(size_t)(qq + r) * N + (n0 + h * 16 + l15)] = f2bf(acc[h][r]);
    __syncthreads();
  }
}

// ---- windowed softmax in place: P = softmax(S/sqrt(128)), zeros beyond window ----
__global__ __launch_bounds__(256) void k_softmax(ushort* __restrict__ S) {
  int rid = blockIdx.x;                // 0..8191 (b*2048+i)
  int i = rid & 2047;
  ushort* row = S + (size_t)rid * 4096;
  int w = i + 2049;                    // keys j <= i + 2048
  int t = threadIdx.x;
  const float scale = 0.08838834764831845f;  // 1/sqrt(128)
  float v[16];
  float mx = -1e30f;
#pragma unroll
  for (int c = 0; c < 16; ++c) {
    int e = c * 256 + t;
    float f = -1e30f;
    if (e < w) f = bf2f(row[e]) * scale;
    v[c] = f;
    mx = fmaxf(mx, f);
  }
  __shared__ float red[4];
#pragma unroll
  for (int off = 32; off; off >>= 1) mx = fmaxf(mx, __shfl_xor(mx, off));
  if ((t & 63) == 0) red[t >> 6] = mx;
  __syncthreads();
  mx = fmaxf(fmaxf(red[0], red[1]), fmaxf(red[2], red[3]));
  __syncthreads();
  float ex[16];
  float sum = 0.f;
#pragma unroll
  for (int c = 0; c < 16; ++c) {
    int e = c * 256 + t;
    ex[c] = (e < w) ? __expf(v[c] - mx) : 0.f;
    sum += ex[c];
  }
#pragma unroll
  for (int off = 32; off; off >>= 1) sum += __shfl_xor(sum, off);
  if ((t & 63) == 0) red[t >> 6] = sum;
  __syncthreads();
  sum = red[0] + red[1] + red[2] + red[3];
  float inv = 1.f / sum;
#pragma unroll
  for (int c = 0; c < 16; ++c) {
    int e = c * 256 + t;
    row[e] = f2bf(ex[c] * inv);        // exact zeros beyond window
  }
}

// ---- PV: O_f32 = P_bf16[2048x4096] . V[4096x128] via Vt; d split over y ----
__global__ __launch_bounds__(128) void k_pv(const ushort* __restrict__ P,
                                            const ushort* __restrict__ Vt,
                                            float* __restrict__ O) {
  int b = blockIdx.z;
  int d0 = blockIdx.y * 64;
  int q0 = blockIdx.x * 32;
  int t = threadIdx.x, lane = t & 63, wv = t >> 6;
  int l15 = lane & 15, q8 = (lane >> 4) * 8;
  const ushort* Pb = P + ((size_t)b * 2048 + q0 + wv * 16 + l15) * 4096;
  const ushort* Vb = Vt + (size_t)b * 128 * 4096;
  int kend = q0 + 32 + 2048; if (kend > 4096) kend = 4096;
  f32x4 zero = {0.f, 0.f, 0.f, 0.f};
  f32x4 acc[4] = {zero, zero, zero, zero};
  for (int k0 = 0; k0 < kend; k0 += 32) {
    bf16x8 af = *(const bf16x8*)(Pb + k0 + q8);
#pragma unroll
    for (int nc = 0; nc < 4; ++nc) {
      bf16x8 bfr = *(const bf16x8*)(Vb + (size_t)(d0 + nc * 16 + l15) * 4096 + k0 + q8);
      acc[nc] = __builtin_amdgcn_mfma_f32_16x16x32_bf16(af, bfr, acc[nc], 0, 0, 0);
    }
  }
  size_t ob = ((size_t)b * 2048 + q0 + wv * 16 + (lane >> 4) * 4) * 128;
#pragma unroll
  for (int nc = 0; nc < 4; ++nc)
#pragma unroll
    for (int r = 0; r < 4; ++r)
      O[ob + (size_t)r * 128 + d0 + nc * 16 + l15] = acc[nc][r];
}

// ---- exact top-32 kNN attention per query: 11-bit radix + parallel scan ----
__global__ __launch_bounds__(256) void k_topk(const ushort* __restrict__ Sall,
                                              const float* __restrict__ qf32b,
                                              const float* __restrict__ memk,
                                              const float* __restrict__ memv,
                                              float* __restrict__ mout) {
  __shared__ uint hist[2048];          // bank-remapped
  __shared__ uint sarr[256];
  __shared__ float qf[128];
  __shared__ uint cidx[384];
  __shared__ float csc[384];
  __shared__ unsigned long long ckey[384];
  __shared__ uint selIdx[32];
  __shared__ float selS[32];
  __shared__ float obuf[256];
  __shared__ int sThr, nC;

  int i = blockIdx.x;
  const ushort* Srow = Sall + (size_t)i * 16384;
  int t = threadIdx.x;
  if (t < 128) qf[t] = qf32b[(size_t)i * 128 + t];
#pragma unroll
  for (int j = 0; j < 8; ++j) hist[j * 256 + t] = 0;
  if (t == 0) nC = 0;
  __syncthreads();

  // pass A: stream scores, 11-bit bucket histogram (bucket = ordkey >> 5)
  for (int c = 0; c < 8; ++c) {
    int base = (c * 256 + t) * 8;
    uint4 rv = *(const uint4*)(Srow + base);
    uint a0 = ord2(rv.x), a1 = ord2(rv.y), a2 = ord2(rv.z), a3 = ord2(rv.w);
    atomicAdd(&hist[haddr((a0 & 0xffffu) >> 5)], 1u); atomicAdd(&hist[haddr(a0 >> 21)], 1u);
    atomicAdd(&hist[haddr((a1 & 0xffffu) >> 5)], 1u); atomicAdd(&hist[haddr(a1 >> 21)], 1u);
    atomicAdd(&hist[haddr((a2 & 0xffffu) >> 5)], 1u); atomicAdd(&hist[haddr(a2 >> 21)], 1u);
    atomicAdd(&hist[haddr((a3 & 0xffffu) >> 5)], 1u); atomicAdd(&hist[haddr(a3 >> 21)], 1u);
  }
  __syncthreads();
  // per-thread suffix over its 8 buckets (bucket b = t*8+j lives at hist[j*256+t])
  uint loc[8];
  {
    uint s = 0;
#pragma unroll
    for (int j = 7; j >= 0; --j) { s += hist[j * 256 + t]; loc[j] = s; }
    sarr[t] = s;
    __syncthreads();
    // Hillis-Steele inclusive suffix across 256 threads
    for (int off = 1; off < 256; off <<= 1) {
      uint v = sarr[t] + ((t + off < 256) ? sarr[t + off] : 0u);
      __syncthreads();
      sarr[t] = v;
      __syncthreads();
    }
    uint above = sarr[t] - s;          // sum over threads > t
    // find max bucket b with C(b) >= 64  (C decreasing in b)
#pragma unroll
    for (int j = 0; j < 8; ++j) {
      uint Cb = loc[j] + above;
      uint Cn = ((j < 7) ? loc[j + 1] : 0u) + above;
      if (Cb >= 64u && Cn < 64u) sThr = ((t * 8 + j) << 5);
    }
  }
  __syncthreads();
  uint T = (uint)sThr;
  // pass B: compact candidate indices with ordkey >= T (count in [64, ~80])
  for (int c = 0; c < 8; ++c) {
    int base = (c * 256 + t) * 8;
    uint4 rv = *(const uint4*)(Srow + base);
    uint hh[8] = {ord2(rv.x) & 0xffffu, ord2(rv.x) >> 16,
                  ord2(rv.y) & 0xffffu, ord2(rv.y) >> 16,
                  ord2(rv.z) & 0xffffu, ord2(rv.z) >> 16,
                  ord2(rv.w) & 0xffffu, ord2(rv.w) >> 16};
#pragma unroll
    for (int j = 0; j < 8; ++j) {
      if (hh[j] >= T) {
        int p = atomicAdd(&nC, 1);
        if (p < 384) cidx[p] = (uint)(base + j);
      }
    }
  }
  __syncthreads();
  int C = nC; if (C > 384) C = 384;
  int wv = t >> 6, lane = t & 63;
  // refine: exact fp32 scores (identical reduction order to validated round-2)
  for (int j = wv; j < C; j += 4) {
    const float* krow = memk + (size_t)cidx[j] * 128;
    float2 pp = *(const float2*)(krow + lane * 2);
    float s = qf[lane * 2] * pp.x + qf[lane * 2 + 1] * pp.y;
#pragma unroll
    for (int off = 32; off; off >>= 1) s += __shfl_xor(s, off);
    if (lane == 0) csc[j] = s;
  }
  __syncthreads();
  // rank-by-counting top-32 (comparator: score desc, index asc — same as round-2)
  for (int j = t; j < C; j += 256) {
    uint sb2 = __float_as_uint(csc[j]);
    uint o = (sb2 & 0x80000000u) ? ~sb2 : (sb2 | 0x80000000u);
    ckey[j] = ((unsigned long long)o << 32) | (uint)(~cidx[j]);
  }
  __syncthreads();
  for (int j = t; j < C; j += 256) {
    unsigned long long my = ckey[j];
    int rank = 0;
    for (int l = 0; l < C; ++l) rank += (ckey[l] > my) ? 1 : 0;
    if (rank < 32) { selS[rank] = csc[j]; selIdx[rank] = cidx[j]; }
  }
  __syncthreads();
  // softmax over the 32 (wave 0, identical math to round-2)
  if (wv == 0) {
    float sc = (lane < 32) ? selS[lane] * 0.03125f : -1e30f;  // 1/sqrt(1024)
    float mx = sc;
#pragma unroll
    for (int off = 32; off; off >>= 1) mx = fmaxf(mx, __shfl_xor(mx, off));
    float ex = (lane < 32) ? __expf(sc - mx) : 0.f;
    float Z = ex;
#pragma unroll
    for (int off = 32; off; off >>= 1) Z += __shfl_xor(Z, off);
    if (lane < 32) selS[lane] = ex / Z;
  }
  __syncthreads();
  // gather: 256 threads, two j-halves per output element
  {
    int d = t & 127, half = t >> 7;
    float acc = 0.f;
    for (int j = half * 16; j < half * 16 + 16; ++j)
      acc += selS[j] * memv[(size_t)selIdx[j] * 128 + d];
    obuf[t] = acc;
  }
  __syncthreads();
  if (t < 128) mout[(size_t)i * 128 + t] = obuf[t] + obuf[t + 128];
}

// ---- final gate mix (fp32 out) ----
__global__ __launch_bounds__(256) void k_mix(const float* __restrict__ a,
                                             const float* __restrict__ b,
                                             const float* __restrict__ gate,
                                             float* __restrict__ out) {
  int id = blockIdx.x * 256 + threadIdx.x;   // 262144 chunks of 4
  float g = gate[0];
  float4 va = ((const float4*)a)[id];
  float4 vb = ((const float4*)b)[id];
  float4 o;
  o.x = va.x * g + vb.x * (1.f - g);
  o.y = va.y * g + vb.y * (1.f - g);
  o.z = va.z * g + vb.z * (1.f - g);
  o.w = va.w * g + vb.w * (1.f - g);
  ((float4*)out)[id] = o;
}

extern "C" void kernel_launch(void* const* d_in, const int* in_sizes, int n_in,
                              void* d_out, int out_size, void* d_ws, size_t ws_size,
                              hipStream_t stream) {
  const float* x    = (const float*)d_in[0];
  const float* ki   = (const float*)d_in[1];
  const float* vi   = (const float*)d_in[2];
  const float* mk   = (const float*)d_in[3];
  const float* mv   = (const float*)d_in[4];
  const float* Wq   = (const float*)d_in[5];
  const float* bq   = (const float*)d_in[6];
  const float* Wk   = (const float*)d_in[7];
  const float* bk   = (const float*)d_in[8];
  const float* Wv   = (const float*)d_in[9];
  const float* bv   = (const float*)d_in[10];
  const float* gate = (const float*)d_in[11];
  const int*   idx  = (const int*)d_in[12];

  char* ws = (char*)d_ws;
  ushort* Sbuf  = (ushort*)(ws);                 // 64 MiB scores (SDPA, then per-batch mem)
  ushort* xh    = (ushort*)(ws);                 // 16 MiB bf16 x hi (pre-SDPA only, inside Sbuf)
  ushort* xl    = (ushort*)(ws + 16777216);      // 16 MiB bf16 x lo (pre-SDPA only)
  float*  qex   = (float*) (ws + 67108864);      // 4 MiB fp32 q (near-exact)
  ushort* kfull = (ushort*)(ws + 71303168);      // 4 MiB
  ushort* vfull = (ushort*)(ws + 75497472);      // 4 MiB
  ushort* Vt    = (ushort*)(ws + 79691776);      // 4 MiB
  ushort* mkb   = (ushort*)(ws + 83886080);      // 16 MiB bf16 mem_keys
  ushort* Wth   = (ushort*)(ws + 100663296);     // 768 KiB
  ushort* Wtlq  = (ushort*)(ws + 101449728);     // 256 KiB
  float*  osdpa = (float*) (ws + 101711872);     // 4 MiB
  float*  mout  = (float*) (ws + 105906176);     // 4 MiB (end ~105 MiB)

  k_wt<<<2048, 256, 0, stream>>>(Wq, Wk, Wv, Wth, Wtlq);
  k_cvt8<<<4096, 256, 0, stream>>>(mk, mkb);     // 4*16384*128 / 8 / 256
  k_xsplit<<<4096, 256, 0, stream>>>(x, xh, xl); // 8192*1024 / 8 / 256
  k_prefix<<<512, 256, 0, stream>>>(ki, vi, idx, kfull, vfull);

  // QKV: one wave per 16 rows, 1536 blocks; bit-identical math to round 3
  k_qkv3<<<dim3(512, 3), 64, 0, stream>>>(xh, xl, Wth, Wtlq, bq, bk, bv,
                                          qex, kfull, vfull);
  k_vt<<<256, 256, 0, stream>>>(vfull, Vt);

  // SDPA: scores -> windowed softmax (in place) -> PV
  k_scores<<<dim3(32, 4, 4), 256, 0, stream>>>(qex, kfull, Sbuf,
                                               4096, 1024, 2048,
                                               (long)2048 * 128, (long)4096 * 128,
                                               (long)2048 * 4096);
  k_softmax<<<8192, 256, 0, stream>>>(Sbuf);
  k_pv<<<dim3(64, 2, 4), 128, 0, stream>>>(Sbuf, Vt, osdpa);

  // kNN memory attention, per batch (reuses Sbuf)
  for (int b = 0; b < 4; ++b) {
    k_scores<<<dim3(32, 8, 1), 256, 0, stream>>>(qex + (size_t)b * 2048 * 128,
                                                 mkb + (size_t)b * 16384 * 128,
                                                 Sbuf, 16384, 2048, (1 << 28),
                                                 0, 0, 0);
    k_topk<<<2048, 256, 0, stream>>>(Sbuf, qex + (size_t)b * 2048 * 128,
                                     mk + (size_t)b * 16384 * 128,
                                     mv + (size_t)b * 16384 * 128,
                                     mout + (size_t)b * 2048 * 128);
  }

  k_mix<<<1024, 256, 0, stream>>>(osdpa, mout, gate, (float*)d_out);
}